// Round 4
// baseline (213.602 us; speedup 1.0000x reference)
//
#include <hip/hip_runtime.h>

#define W      512
#define IMG    (512 * 512)
#define NB     16
#define NPIX   (NB * IMG)

// ---- geometry: 512 uniform hybrid blocks of 1024 threads ----
// each block: loss streaming for one 16-row slab + exact EDT for the same tile
#define TILE_H 16
#define APRON  8
#define LROWS  (TILE_H + 2 * APRON)       // 32
#define BLOCK  1024
#define GRID   (NB * (W / TILE_H))        // 512 == 256 CUs * 2 blocks/CU (100% cap)

struct WS {
    unsigned int vmax[16];        // zeroed each launch; per-batch max int d^2
    float C[NB * W];              // zeroed each launch; C[b,y] = sum_h t*(x-t)^2
    unsigned int counter;         // zeroed each launch; arrival counter
    unsigned int pad[7];
    float rows[NB * W];           // w_edt[b, h=b, y] (sqrt'd)
    float4 partial[GRID];         // .x=sum(x-t)^2  .y=sum p*t  .z=sum p  .w=sum t
};
#define MEMSET_BYTES (sizeof(unsigned int) * 16 + sizeof(float) * NB * W + sizeof(unsigned int))

__device__ __forceinline__ unsigned pk_min_u16(unsigned a, unsigned b) {
    unsigned r; asm("v_pk_min_u16 %0, %1, %2" : "=v"(r) : "v"(a), "v"(b)); return r;
}
__device__ __forceinline__ unsigned pk_max_u16(unsigned a, unsigned b) {
    unsigned r; asm("v_pk_max_u16 %0, %1, %2" : "=v"(r) : "v"(a), "v"(b)); return r;
}

// Exact full-image nearest-zero scan (rare fallback; also handles no-zero case -> BIG)
__device__ int exact_best(const float* __restrict__ img, int h, int y) {
    int best = 100000000;   // reference BIG when no zeros exist
    for (int gh = 0; gh < W; ++gh) {
        int dhh = gh - h;
        if (dhh * dhh >= best) continue;
        const float* rp = img + (gh << 9);
        for (int yy = 0; yy < W; ++yy)
            if (rp[yy] == 0.0f) {
                int dx = yy - y;
                best = min(best, dhh * dhh + dx * dx);
            }
    }
    return best;
}

// Single fused kernel: per-block loss streaming + exact EDT tile, then the LAST
// block (device-scope arrival counter) performs the finalize reduction inline.
//
// EDT: separable bit-trick. Phase 2 stores CLAMPED d^2 (<=65471) as u16.
// Phase 3: each thread owns a y-pair and 4 output rows; loads the 20-row packed
// column once into registers, then 4x17 v_pk_min_u16 with dh^2*0x10001 biases
// (no cross-half carry since 65471+64=65535). Guard: searched set is
// {|dh|<=8, |dx|<=63}; complement d^2 >= 81, so any best<=81 is exact and
// best>81 triggers the exact fallback (statistically never taken).
__global__ __launch_bounds__(BLOCK, 8) void fused_kernel(const float* __restrict__ inp,
                                                         const float* __restrict__ tgt,
                                                         WS* __restrict__ ws,
                                                         float* __restrict__ out) {
    __shared__ unsigned long long zm[LROWS][10];   // 2.5 KB zeros-mask (sentinel cols 0/9)
    __shared__ unsigned short Dd[LROWS][W];        // 32 KB clamped d^2 row profiles
    __shared__ float4 csh[8][128];                 // 16 KB per-(group,y4) column sums
    __shared__ float4 ssum[BLOCK / 64];
    __shared__ unsigned smax[BLOCK / 64];
    __shared__ double shd[BLOCK / 64][5];
    __shared__ float vsh[16];
    __shared__ int sh_last;

    int bid  = blockIdx.x;        // 0..511
    int b    = bid >> 5;          // image
    int tile = bid & 31;
    int h0   = tile * TILE_H;
    int tid  = threadIdx.x;
    int wave = tid >> 6, lane = tid & 63;
    const float* img = tgt + (size_t)b * IMG;

    // ========== loss phase: stream this block's 16-row slab (HBM-bound) ==========
    size_t base4 = (size_t)b * (IMG / 4) + (size_t)tile * (TILE_H * W / 4);
    const float4* x4 = (const float4*)inp + base4;
    const float4* t4 = (const float4*)tgt + base4;

    float s0 = 0.f, s1 = 0.f, s2 = 0.f, s3 = 0.f;
    float4 ct = make_float4(0.f, 0.f, 0.f, 0.f);   // column sums for this thread's y4
    #pragma unroll
    for (int k = 0; k < 2; ++k) {                  // 2048 float4 / 1024 threads
        int i = tid + (k << 10);                   // y4 = i & 127 fixed per thread
        float4 xv = x4[i];
        float4 tv = t4[i];
        { float d = xv.x - tv.x; float e2 = d * d; s0 += e2; ct.x += tv.x * e2;
          float p = 1.0f / (1.0f + __expf(-xv.x)); s1 += p * tv.x; s2 += p; s3 += tv.x; }
        { float d = xv.y - tv.y; float e2 = d * d; s0 += e2; ct.y += tv.y * e2;
          float p = 1.0f / (1.0f + __expf(-xv.y)); s1 += p * tv.y; s2 += p; s3 += tv.y; }
        { float d = xv.z - tv.z; float e2 = d * d; s0 += e2; ct.z += tv.z * e2;
          float p = 1.0f / (1.0f + __expf(-xv.z)); s1 += p * tv.z; s2 += p; s3 += tv.z; }
        { float d = xv.w - tv.w; float e2 = d * d; s0 += e2; ct.w += tv.w * e2;
          float p = 1.0f / (1.0f + __expf(-xv.w)); s1 += p * tv.w; s2 += p; s3 += tv.w; }
    }
    csh[tid >> 7][tid & 127] = ct;
    #pragma unroll
    for (int o = 32; o > 0; o >>= 1) {
        s0 += __shfl_down(s0, o); s1 += __shfl_down(s1, o);
        s2 += __shfl_down(s2, o); s3 += __shfl_down(s3, o);
    }
    if (lane == 0) ssum[wave] = make_float4(s0, s1, s2, s3);

    // ========== EDT phase 1: ballot-pack zeros-mask (core rows L1-hot) ==========
    // disjoint LDS from csh/ssum -> no barrier needed before this
    for (int wi = wave; wi < LROWS * 8; wi += BLOCK / 64) {   // 16 units/wave
        int lr = wi >> 3, wc = wi & 7;
        int gh = h0 - APRON + lr;
        unsigned long long m = 0ULL;
        if (gh >= 0 && gh < W) {
            float v = img[(gh << 9) + (wc << 6) + lane];
            m = __ballot(v == 0.0f);
        }
        if (lane == 0) zm[lr][wc + 1] = m;
    }
    if (tid < LROWS) { zm[tid][0] = 0ULL; zm[tid][9] = 0ULL; }
    __syncthreads();   // barrier 1: zm + csh + ssum ready

    // ========== C-combine (threads 0..128) in parallel with phase 2 ==========
    if (tid < 128) {
        float4 a = csh[0][tid];
        #pragma unroll
        for (int g = 1; g < 8; ++g) {
            float4 c = csh[g][tid];
            a.x += c.x; a.y += c.y; a.z += c.z; a.w += c.w;
        }
        float* Cb = ws->C + (b << 9) + (tid << 2);
        atomicAdd(Cb + 0, a.x);
        atomicAdd(Cb + 1, a.y);
        atomicAdd(Cb + 2, a.z);
        atomicAdd(Cb + 3, a.w);
    } else if (tid == 128) {
        float4 a = ssum[0];
        #pragma unroll
        for (int i = 1; i < BLOCK / 64; ++i) {
            a.x += ssum[i].x; a.y += ssum[i].y; a.z += ssum[i].z; a.w += ssum[i].w;
        }
        ws->partial[bid] = a;
    }

    // ========== EDT phase 2: row profiles, clamped d^2 as u16 ==========
    for (int u = wave; u < LROWS * 8; u += BLOCK / 64) {
        int lr = u >> 3, wc = u & 7;
        unsigned long long Wm = zm[lr][wc];
        unsigned long long Wc = zm[lr][wc + 1];
        unsigned long long Wp = zm[lr][wc + 2];
        int off = lane;
        unsigned long long wr = (Wc >> off) | (off ? (Wp << (64 - off)) : 0ULL);
        int dr = wr ? __builtin_ctzll(wr) : 1000;
        unsigned long long vl = off ? ((Wc << (64 - off)) | (Wm >> off)) : Wm;
        int dl = vl ? (1 + __builtin_clzll(vl)) : 1000;
        int d = min(min(dr, dl), 1000);
        int dd = min(d * d, 65471);              // 65471 + dh^2(<=64) fits u16
        Dd[lr][(wc << 6) + lane] = (unsigned short)dd;
    }
    __syncthreads();   // barrier 2: Dd ready

    // ========== EDT phase 3: register-column packed combine ==========
    // thread -> y-pair p = tid & 255, output-row group q = tid >> 8 (rows 4q..4q+3)
    int p = tid & 255;
    int q = tid >> 8;
    const unsigned* Dd32 = (const unsigned*)&Dd[0][0];   // 256 u32 per row
    const unsigned* basep = Dd32 + (q << 10) + p;        // row 4q, column p
    unsigned col[20];
    #pragma unroll
    for (int j = 0; j < 20; ++j) col[j] = basep[j * 256];

    unsigned best[4];
    #pragma unroll
    for (int m = 0; m < 4; ++m) {
        unsigned bb = 0xFFFFFFFFu;
        #pragma unroll
        for (int j = 0; j <= 16; ++j) {
            unsigned dh2 = (unsigned)((j - 8) * (j - 8));
            bb = pk_min_u16(bb, col[m + j] + dh2 * 0x00010001u);
        }
        best[m] = bb;
    }
    unsigned bpk = pk_max_u16(pk_max_u16(best[0], best[1]), pk_max_u16(best[2], best[3]));
    unsigned tmax = max(bpk & 0xFFFFu, bpk >> 16);

    // ---- rare exact correction (statistically never taken) ----
    if (__builtin_expect(tmax > 81u, 0)) {
        tmax = 0;
        for (int m = 0; m < 4; ++m) {
            int k = (q << 2) + m;
            unsigned nb = 0;
            for (int half = 0; half < 2; ++half) {
                int y = (p << 1) + half;
                int bb = 1 << 30;
                for (int j = 0; j <= 16; ++j)
                    bb = min(bb, (j - 8) * (j - 8) + (int)Dd[k + j][y]);
                if (bb > 81) bb = exact_best(img, h0 + k, y);   // clamped -> true >81 -> exact
                tmax = max(tmax, (unsigned)bb);
                nb |= ((unsigned)bb & 0xFFFFu) << (half * 16);
            }
            best[m] = nb;
        }
    }

    // rows[b, h=b, :] lives in tile 0, local row k=b
    if (tile == 0 && q == (b >> 2)) {
        unsigned rb = best[b & 3];
        ws->rows[(b << 9) + (p << 1)]     = sqrtf((float)(rb & 0xFFFFu));
        ws->rows[(b << 9) + (p << 1) + 1] = sqrtf((float)(rb >> 16));
    }

    // block max (int d^2; sqrt is monotone) -> atomicMax
    #pragma unroll
    for (int o = 32; o > 0; o >>= 1) tmax = max(tmax, (unsigned)__shfl_down(tmax, o));
    if (lane == 0) smax[wave] = tmax;
    __syncthreads();   // barrier 3: smax ready
    if (tid == 0) {
        unsigned bm = smax[0];
        #pragma unroll
        for (int i = 1; i < BLOCK / 64; ++i) bm = max(bm, smax[i]);
        atomicMax(&ws->vmax[b], bm);
    }

    // ========== arrival: last block finalizes ==========
    __threadfence();     // each thread releases its own stores (rows/partial/atomics)
    __syncthreads();     // all fences in this block done
    if (tid == 0) {
        unsigned old = atomicAdd(&ws->counter, 1u);
        sh_last = (old == GRID - 1);
    }
    __syncthreads();
    if (!sh_last) return;
    __threadfence();     // acquire

    // -------- finalize (one block, 1024 threads) --------
    //   wmse_sum = sum_{b,y} C[b,y]*(v_b - rows[b,y]) + EPS_W * E   (all terms >= 0)
    //   dice     = 1 - (2*s1 + 1e-6)/(s2 + s3 + 1e-6)
    if (tid < 16) vsh[tid] = sqrtf((float)((volatile unsigned*)ws->vmax)[tid]);
    __syncthreads();

    double wm = 0.0;
    #pragma unroll
    for (int j = 0; j < (NB * W) / BLOCK; ++j) {   // 8 cells/thread
        int cell = tid + (j << 10);
        float c = ((volatile float*)ws->C)[cell];
        float r = ((volatile float*)ws->rows)[cell];
        wm += (double)c * (double)(vsh[cell >> 9] - r);
    }
    double e = 0, t1 = 0, t2 = 0, t3 = 0;
    if (tid < GRID) {
        volatile float* pp = (volatile float*)&ws->partial[tid];
        e = pp[0]; t1 = pp[1]; t2 = pp[2]; t3 = pp[3];
    }

    #pragma unroll
    for (int o = 32; o > 0; o >>= 1) {
        wm += __shfl_down(wm, o); e  += __shfl_down(e, o);
        t1 += __shfl_down(t1, o); t2 += __shfl_down(t2, o); t3 += __shfl_down(t3, o);
    }
    if (lane == 0) { shd[wave][0] = wm; shd[wave][1] = e;
                     shd[wave][2] = t1; shd[wave][3] = t2; shd[wave][4] = t3; }
    __syncthreads();
    if (tid == 0) {
        double a0 = 0, a1 = 0, a2 = 0, a3 = 0, a4 = 0;
        #pragma unroll
        for (int i = 0; i < BLOCK / 64; ++i) {
            a0 += shd[i][0]; a1 += shd[i][1]; a2 += shd[i][2]; a3 += shd[i][3]; a4 += shd[i][4];
        }
        double wmse = (a0 + 0.001 * a1) / (double)NPIX;
        out[0] = (float)(0.6 * wmse);
        out[1] = (float)(1.0 - (2.0 * a2 + 1e-6) / (a3 + a4 + 1e-6));
    }
}

extern "C" void kernel_launch(void* const* d_in, const int* in_sizes, int n_in,
                              void* d_out, int out_size, void* d_ws, size_t ws_size,
                              hipStream_t stream) {
    const float* inp = (const float*)d_in[0];
    const float* tgt = (const float*)d_in[1];
    float* out = (float*)d_out;
    WS* ws = (WS*)d_ws;

    // zero vmax + C + counter (contiguous at struct start); rows/partial fully overwritten
    hipMemsetAsync(d_ws, 0, MEMSET_BYTES, stream);
    fused_kernel<<<GRID, BLOCK, 0, stream>>>(inp, tgt, ws, out);
}

// Round 5
// 90.711 us; speedup vs baseline: 2.3548x; 2.3548x over previous
//
#include <hip/hip_runtime.h>

#define W      512
#define IMG    (512 * 512)
#define NB     16
#define NPIX   (NB * IMG)

// ---- geometry: 512 uniform hybrid blocks of 1024 threads ----
// each block: loss streaming for one 16-row slab + exact EDT for the same tile
#define TILE_H 16
#define APRON  4
#define LROWS  (TILE_H + 2 * APRON)       // 24
#define BLOCK  1024
#define GRID   (NB * (W / TILE_H))        // 512 == 256 CUs * 2 blocks/CU (100% cap)

struct WS {
    unsigned int vmax[16];        // zeroed each launch; per-batch max int d^2
    float C[NB * W];              // zeroed each launch; C[b,y] = sum_h t*(x-t)^2
    float rows[NB * W];           // w_edt[b, h=b, y] (sqrt'd)
    float4 partial[GRID];         // .x=sum(x-t)^2  .y=sum p*t  .z=sum p  .w=sum t
};
#define MEMSET_BYTES (sizeof(unsigned int) * 16 + sizeof(float) * NB * W)

__device__ __forceinline__ unsigned pk_min_u16(unsigned a, unsigned b) {
    unsigned r; asm("v_pk_min_u16 %0, %1, %2" : "=v"(r) : "v"(a), "v"(b)); return r;
}
__device__ __forceinline__ unsigned pk_max_u16(unsigned a, unsigned b) {
    unsigned r; asm("v_pk_max_u16 %0, %1, %2" : "=v"(r) : "v"(a), "v"(b)); return r;
}

// Exact full-image nearest-zero scan (rare fallback; also handles no-zero case -> BIG)
__device__ int exact_best(const float* __restrict__ img, int h, int y) {
    int best = 100000000;   // reference BIG when no zeros exist
    for (int gh = 0; gh < W; ++gh) {
        int dhh = gh - h;
        if (dhh * dhh >= best) continue;
        const float* rp = img + (gh << 9);
        for (int yy = 0; yy < W; ++yy)
            if (rp[yy] == 0.0f) {
                int dx = yy - y;
                best = min(best, dhh * dhh + dx * dx);
            }
    }
    return best;
}

// Fused kernel: per-block loss streaming + exact EDT tile.
//
// EDT: separable bit-trick. Phase 2 stores CLAMPED d^2 (<=65471) as u16.
// Phase 3: each thread owns a y-pair and 4 output rows; loads the 12-row packed
// column once into registers, then 4x9 v_pk_min_u16 with dh^2*0x10001 biases
// (no cross-half carry since 65471+16=65487<65536). Guard: searched set is
// {|dh|<=4, |dx|<=63}; complement d^2 >= min(25,4096) > 16, so any best<=16 is
// exact and best>16 triggers the exact fallback (statistically never taken:
// needs an all-ones disk of radius 5, P ~ 2^-78 per pixel).
__global__ __launch_bounds__(BLOCK, 8) void fused_kernel(const float* __restrict__ inp,
                                                         const float* __restrict__ tgt,
                                                         WS* __restrict__ ws) {
    __shared__ unsigned long long zm[LROWS][10];   // 1.9 KB zeros-mask (sentinel cols 0/9)
    __shared__ unsigned short Dd[LROWS][W];        // 24 KB clamped d^2 row profiles
    __shared__ float4 csh[8][128];                 // 16 KB per-(group,y4) column sums
    __shared__ float4 ssum[BLOCK / 64];
    __shared__ unsigned smax[BLOCK / 64];

    int bid  = blockIdx.x;        // 0..511
    int b    = bid >> 5;          // image
    int tile = bid & 31;
    int h0   = tile * TILE_H;
    int tid  = threadIdx.x;
    int wave = tid >> 6, lane = tid & 63;
    const float* img = tgt + (size_t)b * IMG;

    // ========== loss phase: stream this block's 16-row slab (HBM-bound) ==========
    size_t base4 = (size_t)b * (IMG / 4) + (size_t)tile * (TILE_H * W / 4);
    const float4* x4 = (const float4*)inp + base4;
    const float4* t4 = (const float4*)tgt + base4;

    float s0 = 0.f, s1 = 0.f, s2 = 0.f, s3 = 0.f;
    float4 ct = make_float4(0.f, 0.f, 0.f, 0.f);   // column sums for this thread's y4
    #pragma unroll
    for (int k = 0; k < 2; ++k) {                  // 2048 float4 / 1024 threads
        int i = tid + (k << 10);                   // y4 = i & 127 fixed per thread
        float4 xv = x4[i];
        float4 tv = t4[i];
        { float d = xv.x - tv.x; float e2 = d * d; s0 += e2; ct.x += tv.x * e2;
          float p = 1.0f / (1.0f + __expf(-xv.x)); s1 += p * tv.x; s2 += p; s3 += tv.x; }
        { float d = xv.y - tv.y; float e2 = d * d; s0 += e2; ct.y += tv.y * e2;
          float p = 1.0f / (1.0f + __expf(-xv.y)); s1 += p * tv.y; s2 += p; s3 += tv.y; }
        { float d = xv.z - tv.z; float e2 = d * d; s0 += e2; ct.z += tv.z * e2;
          float p = 1.0f / (1.0f + __expf(-xv.z)); s1 += p * tv.z; s2 += p; s3 += tv.z; }
        { float d = xv.w - tv.w; float e2 = d * d; s0 += e2; ct.w += tv.w * e2;
          float p = 1.0f / (1.0f + __expf(-xv.w)); s1 += p * tv.w; s2 += p; s3 += tv.w; }
    }
    csh[tid >> 7][tid & 127] = ct;
    #pragma unroll
    for (int o = 32; o > 0; o >>= 1) {
        s0 += __shfl_down(s0, o); s1 += __shfl_down(s1, o);
        s2 += __shfl_down(s2, o); s3 += __shfl_down(s3, o);
    }
    if (lane == 0) ssum[wave] = make_float4(s0, s1, s2, s3);

    // ========== EDT phase 1: ballot-pack zeros-mask (core rows L1-hot) ==========
    // disjoint LDS from csh/ssum -> no barrier needed before this
    for (int wi = wave; wi < LROWS * 8; wi += BLOCK / 64) {   // 12 units/wave
        int lr = wi >> 3, wc = wi & 7;
        int gh = h0 - APRON + lr;
        unsigned long long m = 0ULL;
        if (gh >= 0 && gh < W) {
            float v = img[(gh << 9) + (wc << 6) + lane];
            m = __ballot(v == 0.0f);
        }
        if (lane == 0) zm[lr][wc + 1] = m;
    }
    if (tid < LROWS) { zm[tid][0] = 0ULL; zm[tid][9] = 0ULL; }
    __syncthreads();   // barrier 1: zm + csh + ssum ready

    // ========== C-combine (waves 0-2) in parallel with phase 2 (all waves) ==========
    if (tid < 128) {
        float4 a = csh[0][tid];
        #pragma unroll
        for (int g = 1; g < 8; ++g) {
            float4 c = csh[g][tid];
            a.x += c.x; a.y += c.y; a.z += c.z; a.w += c.w;
        }
        float* Cb = ws->C + (b << 9) + (tid << 2);
        atomicAdd(Cb + 0, a.x);
        atomicAdd(Cb + 1, a.y);
        atomicAdd(Cb + 2, a.z);
        atomicAdd(Cb + 3, a.w);
    } else if (tid == 128) {
        float4 a = ssum[0];
        #pragma unroll
        for (int i = 1; i < BLOCK / 64; ++i) {
            a.x += ssum[i].x; a.y += ssum[i].y; a.z += ssum[i].z; a.w += ssum[i].w;
        }
        ws->partial[bid] = a;
    }

    // ========== EDT phase 2: row profiles, clamped d^2 as u16 ==========
    for (int u = wave; u < LROWS * 8; u += BLOCK / 64) {
        int lr = u >> 3, wc = u & 7;
        unsigned long long Wm = zm[lr][wc];
        unsigned long long Wc = zm[lr][wc + 1];
        unsigned long long Wp = zm[lr][wc + 2];
        int off = lane;
        unsigned long long wr = (Wc >> off) | (off ? (Wp << (64 - off)) : 0ULL);
        int dr = wr ? __builtin_ctzll(wr) : 1000;
        unsigned long long vl = off ? ((Wc << (64 - off)) | (Wm >> off)) : Wm;
        int dl = vl ? (1 + __builtin_clzll(vl)) : 1000;
        int d = min(min(dr, dl), 1000);
        int dd = min(d * d, 65471);              // 65471 + dh^2(<=16) fits u16
        Dd[lr][(wc << 6) + lane] = (unsigned short)dd;
    }
    __syncthreads();   // barrier 2: Dd ready

    // ========== EDT phase 3: register-column packed combine ==========
    // thread -> y-pair p = tid & 255, output-row group q = tid >> 8 (rows 4q..4q+3)
    int p = tid & 255;
    int q = tid >> 8;
    const unsigned* Dd32 = (const unsigned*)&Dd[0][0];   // 256 u32 per row
    const unsigned* basep = Dd32 + (q << 10) + p;        // row 4q, column p
    unsigned col[12];
    #pragma unroll
    for (int j = 0; j < 12; ++j) col[j] = basep[j * 256];

    unsigned best[4];
    #pragma unroll
    for (int m = 0; m < 4; ++m) {
        unsigned bb = 0xFFFFFFFFu;
        #pragma unroll
        for (int j = 0; j <= 8; ++j) {
            unsigned dh2 = (unsigned)((j - 4) * (j - 4));
            bb = pk_min_u16(bb, col[m + j] + dh2 * 0x00010001u);
        }
        best[m] = bb;
    }
    unsigned bpk = pk_max_u16(pk_max_u16(best[0], best[1]), pk_max_u16(best[2], best[3]));
    unsigned tmax = max(bpk & 0xFFFFu, bpk >> 16);

    // ---- rare exact correction (statistically never taken) ----
    if (__builtin_expect(tmax > 16u, 0)) {
        tmax = 0;
        for (int m = 0; m < 4; ++m) {
            int k = (q << 2) + m;
            unsigned nb = 0;
            for (int half = 0; half < 2; ++half) {
                int y = (p << 1) + half;
                int bb = 1 << 30;
                for (int j = 0; j <= 8; ++j)
                    bb = min(bb, (j - 4) * (j - 4) + (int)Dd[k + j][y]);
                if (bb > 16) bb = exact_best(img, h0 + k, y);   // clamped -> true >16 -> exact
                tmax = max(tmax, (unsigned)bb);
                nb |= ((unsigned)bb & 0xFFFFu) << (half * 16);
            }
            best[m] = nb;
        }
    }

    // rows[b, h=b, :] lives in tile 0, local row k=b
    if (tile == 0 && q == (b >> 2)) {
        unsigned rb = best[b & 3];
        ws->rows[(b << 9) + (p << 1)]     = sqrtf((float)(rb & 0xFFFFu));
        ws->rows[(b << 9) + (p << 1) + 1] = sqrtf((float)(rb >> 16));
    }

    // block max (int d^2; sqrt is monotone) -> atomicMax
    #pragma unroll
    for (int o = 32; o > 0; o >>= 1) tmax = max(tmax, (unsigned)__shfl_down(tmax, o));
    if (lane == 0) smax[wave] = tmax;
    __syncthreads();   // barrier 3: smax ready
    if (tid == 0) {
        unsigned bm = smax[0];
        #pragma unroll
        for (int i = 1; i < BLOCK / 64; ++i) bm = max(bm, smax[i]);
        atomicMax(&ws->vmax[b], bm);
    }
}

// Single-block finalize:
//   wmse_sum = sum_{b,y} C[b,y]*(v_b - rows[b,y]) + EPS_W * E   (all terms >= 0)
//   dice     = 1 - (2*s1 + 1e-6)/(s2 + s3 + 1e-6)
#define FBLOCK 256
__global__ __launch_bounds__(FBLOCK) void final_kernel(const WS* __restrict__ ws,
                                                       float* __restrict__ out) {
    int tid = threadIdx.x;
    __shared__ float vsh[16];
    if (tid < 16) vsh[tid] = sqrtf((float)ws->vmax[tid]);
    __syncthreads();

    double wm = 0.0;
    #pragma unroll
    for (int j = 0; j < (NB * W) / FBLOCK; ++j) {   // 32 cells/thread
        int cell = tid + j * FBLOCK;
        wm += (double)ws->C[cell] * (double)(vsh[cell >> 9] - ws->rows[cell]);
    }
    double e = 0, s1 = 0, s2 = 0, s3 = 0;
    #pragma unroll
    for (int j = 0; j < GRID / FBLOCK; ++j) {       // 2
        float4 p = ws->partial[tid + j * FBLOCK];
        e += p.x; s1 += p.y; s2 += p.z; s3 += p.w;
    }

    #pragma unroll
    for (int o = 32; o > 0; o >>= 1) {
        wm += __shfl_down(wm, o); e  += __shfl_down(e, o);
        s1 += __shfl_down(s1, o); s2 += __shfl_down(s2, o); s3 += __shfl_down(s3, o);
    }
    __shared__ double shd[FBLOCK / 64][5];
    int lane = tid & 63, wid = tid >> 6;
    if (lane == 0) { shd[wid][0] = wm; shd[wid][1] = e;
                     shd[wid][2] = s1; shd[wid][3] = s2; shd[wid][4] = s3; }
    __syncthreads();
    if (tid == 0) {
        double a0 = 0, a1 = 0, a2 = 0, a3 = 0, a4 = 0;
        #pragma unroll
        for (int i = 0; i < FBLOCK / 64; ++i) {
            a0 += shd[i][0]; a1 += shd[i][1]; a2 += shd[i][2]; a3 += shd[i][3]; a4 += shd[i][4];
        }
        double wmse = (a0 + 0.001 * a1) / (double)NPIX;
        out[0] = (float)(0.6 * wmse);
        out[1] = (float)(1.0 - (2.0 * a2 + 1e-6) / (a3 + a4 + 1e-6));
    }
}

extern "C" void kernel_launch(void* const* d_in, const int* in_sizes, int n_in,
                              void* d_out, int out_size, void* d_ws, size_t ws_size,
                              hipStream_t stream) {
    const float* inp = (const float*)d_in[0];
    const float* tgt = (const float*)d_in[1];
    float* out = (float*)d_out;
    WS* ws = (WS*)d_ws;

    // zero vmax + C (contiguous at struct start); rows/partial fully overwritten
    hipMemsetAsync(d_ws, 0, MEMSET_BYTES, stream);
    fused_kernel<<<GRID, BLOCK, 0, stream>>>(inp, tgt, ws);
    final_kernel<<<1, FBLOCK, 0, stream>>>(ws, out);
}

// Round 6
// 90.105 us; speedup vs baseline: 2.3706x; 1.0067x over previous
//
#include <hip/hip_runtime.h>

#define W      512
#define IMG    (512 * 512)
#define NB     16
#define NPIX   (NB * IMG)

// ---- geometry: 512 uniform hybrid blocks of 1024 threads ----
// each block: loss streaming for one 16-row slab + exact EDT for the same tile
#define TILE_H 16
#define APRON  4
#define LROWS  (TILE_H + 2 * APRON)       // 24
#define BLOCK  1024
#define GRID   (NB * (W / TILE_H))        // 512 == 256 CUs * 2 blocks/CU (100% cap)

struct WS {
    unsigned int vmax[16];        // zeroed each launch; per-batch max int d^2
    float C[NB * W];              // zeroed each launch; C[b,y] = sum_h t*(x-t)^2
    float rows[NB * W];           // w_edt[b, h=b, y] (sqrt'd)
    float4 partial[GRID];         // .x=sum(x-t)^2  .y=sum p*t  .z=sum p  .w=sum t
};
#define MEMSET_BYTES (sizeof(unsigned int) * 16 + sizeof(float) * NB * W)

__device__ __forceinline__ unsigned pk_min_u16(unsigned a, unsigned b) {
    unsigned r; asm("v_pk_min_u16 %0, %1, %2" : "=v"(r) : "v"(a), "v"(b)); return r;
}
__device__ __forceinline__ unsigned pk_max_u16(unsigned a, unsigned b) {
    unsigned r; asm("v_pk_max_u16 %0, %1, %2" : "=v"(r) : "v"(a), "v"(b)); return r;
}

// Exact full-image nearest-zero scan (rare fallback; also handles no-zero case -> BIG)
__device__ int exact_best(const float* __restrict__ img, int h, int y) {
    int best = 100000000;   // reference BIG when no zeros exist
    for (int gh = 0; gh < W; ++gh) {
        int dhh = gh - h;
        if (dhh * dhh >= best) continue;
        const float* rp = img + (gh << 9);
        for (int yy = 0; yy < W; ++yy)
            if (rp[yy] == 0.0f) {
                int dx = yy - y;
                best = min(best, dhh * dhh + dx * dx);
            }
    }
    return best;
}

// Fused kernel: per-block loss streaming + exact EDT tile.
//
// EDT: separable bit-trick. Core-row zero-masks are packed IN-REGISTER during
// the loss stream (nibble per lane + OR-butterfly over 16-lane groups); only
// the 8 apron rows are loaded separately (prefetched before the loss loop).
// Phase 2 stores CLAMPED d^2 (<=65471) as u16. Phase 3: each thread owns a
// y-pair and 4 output rows; loads the 12-row packed column into registers,
// then 4x9 v_pk_min_u16 with dh^2*0x10001 biases (no cross-half carry since
// 65471+16=65487<65536). Guard: searched set is {|dh|<=4, |dx|<=63};
// complement d^2 >= min(25,4096) > 16, so any best<=16 is exact and best>16
// triggers the exact fallback (statistically never taken: needs an all-ones
// disk of radius 5, P ~ 2^-78 per pixel).
__global__ __launch_bounds__(BLOCK, 8) void fused_kernel(const float* __restrict__ inp,
                                                         const float* __restrict__ tgt,
                                                         WS* __restrict__ ws) {
    __shared__ unsigned long long zm[LROWS][10];   // 1.9 KB zeros-mask (sentinel cols 0/9)
    __shared__ unsigned short Dd[LROWS][W];        // 24 KB clamped d^2 row profiles
    __shared__ float4 csh[8][128];                 // 16 KB per-(group,y4) column sums
    __shared__ float4 ssum[BLOCK / 64];
    __shared__ unsigned smax[BLOCK / 64];

    int bid  = blockIdx.x;        // 0..511
    int b    = bid >> 5;          // image
    int tile = bid & 31;
    int h0   = tile * TILE_H;
    int tid  = threadIdx.x;
    int wave = tid >> 6, lane = tid & 63;
    const float* img = tgt + (size_t)b * IMG;

    // ---- apron prefetch: 64 (row,word) units over 16 waves = 4 per wave ----
    // issued BEFORE the loss stream; consumed (ballot) after it.
    float av[4];
    #pragma unroll
    for (int j = 0; j < 4; ++j) {
        int aa = (wave << 2) + j;
        int ar = aa >> 3;                       // 0..7 apron-row index
        int lr = ar < 4 ? ar : ar + 16;         // 0..3 top, 20..23 bottom
        int wc = aa & 7;
        int gh = h0 - APRON + lr;
        av[j] = (gh >= 0 && gh < W) ? img[(gh << 9) + (wc << 6) + lane] : 1.0f;
    }

    // ========== loss phase: stream this block's 16-row slab (HBM-bound) ==========
    size_t base4 = (size_t)b * (IMG / 4) + (size_t)tile * (TILE_H * W / 4);
    const float4* x4 = (const float4*)inp + base4;
    const float4* t4 = (const float4*)tgt + base4;

    float s0 = 0.f, s1 = 0.f, s2 = 0.f, s3 = 0.f;
    float4 ct = make_float4(0.f, 0.f, 0.f, 0.f);   // column sums for this thread's y4
    #pragma unroll
    for (int k = 0; k < 2; ++k) {                  // 2048 float4 / 1024 threads
        int i = tid + (k << 10);                   // y4 = i & 127 fixed per thread
        float4 xv = x4[i];
        float4 tv = t4[i];
        { float d = xv.x - tv.x; float e2 = d * d; s0 += e2; ct.x += tv.x * e2;
          float p = 1.0f / (1.0f + __expf(-xv.x)); s1 += p * tv.x; s2 += p; s3 += tv.x; }
        { float d = xv.y - tv.y; float e2 = d * d; s0 += e2; ct.y += tv.y * e2;
          float p = 1.0f / (1.0f + __expf(-xv.y)); s1 += p * tv.y; s2 += p; s3 += tv.y; }
        { float d = xv.z - tv.z; float e2 = d * d; s0 += e2; ct.z += tv.z * e2;
          float p = 1.0f / (1.0f + __expf(-xv.z)); s1 += p * tv.z; s2 += p; s3 += tv.z; }
        { float d = xv.w - tv.w; float e2 = d * d; s0 += e2; ct.w += tv.w * e2;
          float p = 1.0f / (1.0f + __expf(-xv.w)); s1 += p * tv.w; s2 += p; s3 += tv.w; }

        // ---- pack this row-half's zero-mask in-register (free under HBM stalls) ----
        // wave w, iter k covers row r=(w>>1)+8k, half=(w&1); lane l holds bits
        // 4*(l&15)..+3 of 64-bit word (l>>4) of that half.
        unsigned nib = (tv.x == 0.f ? 1u : 0u) | (tv.y == 0.f ? 2u : 0u)
                     | (tv.z == 0.f ? 4u : 0u) | (tv.w == 0.f ? 8u : 0u);
        unsigned long long contrib = (unsigned long long)nib << ((lane & 15) << 2);
        #pragma unroll
        for (int m = 1; m <= 8; m <<= 1) contrib |= __shfl_xor(contrib, m);
        if ((lane & 15) == 0) {
            int r = (wave >> 1) + (k << 3);
            zm[APRON + r][((wave & 1) << 2) + (lane >> 4) + 1] = contrib;
        }
    }
    csh[tid >> 7][tid & 127] = ct;
    #pragma unroll
    for (int o = 32; o > 0; o >>= 1) {
        s0 += __shfl_down(s0, o); s1 += __shfl_down(s1, o);
        s2 += __shfl_down(s2, o); s3 += __shfl_down(s3, o);
    }
    if (lane == 0) ssum[wave] = make_float4(s0, s1, s2, s3);

    // ---- apron ballots (prefetched values; OOB lanes forced non-zero) ----
    #pragma unroll
    for (int j = 0; j < 4; ++j) {
        int aa = (wave << 2) + j;
        int ar = aa >> 3;
        int lr = ar < 4 ? ar : ar + 16;
        int wc = aa & 7;
        unsigned long long m = __ballot(av[j] == 0.0f);
        if (lane == 0) zm[lr][wc + 1] = m;
    }
    if (tid < LROWS) { zm[tid][0] = 0ULL; zm[tid][9] = 0ULL; }
    __syncthreads();   // barrier 1: zm + csh + ssum ready

    // ========== EDT phase 2: row profiles, clamped d^2 as u16 ==========
    for (int u = wave; u < LROWS * 8; u += BLOCK / 64) {   // 12 units/wave
        int lr = u >> 3, wc = u & 7;
        unsigned long long Wm = zm[lr][wc];
        unsigned long long Wc = zm[lr][wc + 1];
        unsigned long long Wp = zm[lr][wc + 2];
        int off = lane;
        unsigned long long wr = (Wc >> off) | (off ? (Wp << (64 - off)) : 0ULL);
        int dr = wr ? __builtin_ctzll(wr) : 1000;
        unsigned long long vl = off ? ((Wc << (64 - off)) | (Wm >> off)) : Wm;
        int dl = vl ? (1 + __builtin_clzll(vl)) : 1000;
        int d = min(min(dr, dl), 1000);
        int dd = min(d * d, 65471);              // 65471 + dh^2(<=16) fits u16
        Dd[lr][(wc << 6) + lane] = (unsigned short)dd;
    }

    // ---- C-combine AFTER phase 2: atomics are fire-and-forget, off the
    //      barrier-2 critical path (nothing reads C until final_kernel) ----
    if (tid < 128) {
        float4 a = csh[0][tid];
        #pragma unroll
        for (int g = 1; g < 8; ++g) {
            float4 c = csh[g][tid];
            a.x += c.x; a.y += c.y; a.z += c.z; a.w += c.w;
        }
        float* Cb = ws->C + (b << 9) + (tid << 2);
        atomicAdd(Cb + 0, a.x);
        atomicAdd(Cb + 1, a.y);
        atomicAdd(Cb + 2, a.z);
        atomicAdd(Cb + 3, a.w);
    } else if (tid == 128) {
        float4 a = ssum[0];
        #pragma unroll
        for (int i = 1; i < BLOCK / 64; ++i) {
            a.x += ssum[i].x; a.y += ssum[i].y; a.z += ssum[i].z; a.w += ssum[i].w;
        }
        ws->partial[bid] = a;
    }
    __syncthreads();   // barrier 2: Dd ready

    // ========== EDT phase 3: register-column packed combine ==========
    // thread -> y-pair p = tid & 255, output-row group q = tid >> 8 (rows 4q..4q+3)
    int p = tid & 255;
    int q = tid >> 8;
    const unsigned* Dd32 = (const unsigned*)&Dd[0][0];   // 256 u32 per row
    const unsigned* basep = Dd32 + (q << 10) + p;        // row 4q, column p
    unsigned col[12];
    #pragma unroll
    for (int j = 0; j < 12; ++j) col[j] = basep[j * 256];

    unsigned best[4];
    #pragma unroll
    for (int m = 0; m < 4; ++m) {
        unsigned bb = 0xFFFFFFFFu;
        #pragma unroll
        for (int j = 0; j <= 8; ++j) {
            unsigned dh2 = (unsigned)((j - 4) * (j - 4));
            bb = pk_min_u16(bb, col[m + j] + dh2 * 0x00010001u);
        }
        best[m] = bb;
    }
    unsigned bpk = pk_max_u16(pk_max_u16(best[0], best[1]), pk_max_u16(best[2], best[3]));
    unsigned tmax = max(bpk & 0xFFFFu, bpk >> 16);

    // ---- rare exact correction (statistically never taken) ----
    if (__builtin_expect(tmax > 16u, 0)) {
        tmax = 0;
        for (int m = 0; m < 4; ++m) {
            int k = (q << 2) + m;
            unsigned nb = 0;
            for (int half = 0; half < 2; ++half) {
                int y = (p << 1) + half;
                int bb = 1 << 30;
                for (int j = 0; j <= 8; ++j)
                    bb = min(bb, (j - 4) * (j - 4) + (int)Dd[k + j][y]);
                if (bb > 16) bb = exact_best(img, h0 + k, y);   // clamped -> true >16 -> exact
                tmax = max(tmax, (unsigned)bb);
                nb |= ((unsigned)bb & 0xFFFFu) << (half * 16);
            }
            best[m] = nb;
        }
    }

    // rows[b, h=b, :] lives in tile 0, local row k=b
    if (tile == 0 && q == (b >> 2)) {
        unsigned rb = best[b & 3];
        ws->rows[(b << 9) + (p << 1)]     = sqrtf((float)(rb & 0xFFFFu));
        ws->rows[(b << 9) + (p << 1) + 1] = sqrtf((float)(rb >> 16));
    }

    // block max (int d^2; sqrt is monotone) -> atomicMax
    #pragma unroll
    for (int o = 32; o > 0; o >>= 1) tmax = max(tmax, (unsigned)__shfl_down(tmax, o));
    if (lane == 0) smax[wave] = tmax;
    __syncthreads();   // barrier 3: smax ready
    if (tid == 0) {
        unsigned bm = smax[0];
        #pragma unroll
        for (int i = 1; i < BLOCK / 64; ++i) bm = max(bm, smax[i]);
        atomicMax(&ws->vmax[b], bm);
    }
}

// Single-block finalize:
//   wmse_sum = sum_{b,y} C[b,y]*(v_b - rows[b,y]) + EPS_W * E   (all terms >= 0)
//   dice     = 1 - (2*s1 + 1e-6)/(s2 + s3 + 1e-6)
#define FBLOCK 256
__global__ __launch_bounds__(FBLOCK) void final_kernel(const WS* __restrict__ ws,
                                                       float* __restrict__ out) {
    int tid = threadIdx.x;
    __shared__ float vsh[16];
    if (tid < 16) vsh[tid] = sqrtf((float)ws->vmax[tid]);
    __syncthreads();

    double wm = 0.0;
    #pragma unroll
    for (int j = 0; j < (NB * W) / FBLOCK; ++j) {   // 32 cells/thread
        int cell = tid + j * FBLOCK;
        wm += (double)ws->C[cell] * (double)(vsh[cell >> 9] - ws->rows[cell]);
    }
    double e = 0, s1 = 0, s2 = 0, s3 = 0;
    #pragma unroll
    for (int j = 0; j < GRID / FBLOCK; ++j) {       // 2
        float4 p = ws->partial[tid + j * FBLOCK];
        e += p.x; s1 += p.y; s2 += p.z; s3 += p.w;
    }

    #pragma unroll
    for (int o = 32; o > 0; o >>= 1) {
        wm += __shfl_down(wm, o); e  += __shfl_down(e, o);
        s1 += __shfl_down(s1, o); s2 += __shfl_down(s2, o); s3 += __shfl_down(s3, o);
    }
    __shared__ double shd[FBLOCK / 64][5];
    int lane = tid & 63, wid = tid >> 6;
    if (lane == 0) { shd[wid][0] = wm; shd[wid][1] = e;
                     shd[wid][2] = s1; shd[wid][3] = s2; shd[wid][4] = s3; }
    __syncthreads();
    if (tid == 0) {
        double a0 = 0, a1 = 0, a2 = 0, a3 = 0, a4 = 0;
        #pragma unroll
        for (int i = 0; i < FBLOCK / 64; ++i) {
            a0 += shd[i][0]; a1 += shd[i][1]; a2 += shd[i][2]; a3 += shd[i][3]; a4 += shd[i][4];
        }
        double wmse = (a0 + 0.001 * a1) / (double)NPIX;
        out[0] = (float)(0.6 * wmse);
        out[1] = (float)(1.0 - (2.0 * a2 + 1e-6) / (a3 + a4 + 1e-6));
    }
}

extern "C" void kernel_launch(void* const* d_in, const int* in_sizes, int n_in,
                              void* d_out, int out_size, void* d_ws, size_t ws_size,
                              hipStream_t stream) {
    const float* inp = (const float*)d_in[0];
    const float* tgt = (const float*)d_in[1];
    float* out = (float*)d_out;
    WS* ws = (WS*)d_ws;

    // zero vmax + C (contiguous at struct start); rows/partial fully overwritten
    hipMemsetAsync(d_ws, 0, MEMSET_BYTES, stream);
    fused_kernel<<<GRID, BLOCK, 0, stream>>>(inp, tgt, ws);
    final_kernel<<<1, FBLOCK, 0, stream>>>(ws, out);
}